// Round 4
// baseline (390.608 us; speedup 1.0000x reference)
//
#include <hip/hip_runtime.h>
#include <hip/hip_bf16.h>
#include <cmath>

// ---------------------------------------------------------------------------
// HeavyEncoderLayer, MI355X. R4: software-pipelined B-loads (register
// double-buffer) in k2 and k3; k2 LDS diet (40KB) via cf000t==a0*x0pt merge;
// padded LDS accumulators to break 4-way flush bank conflicts.
// ---------------------------------------------------------------------------

#define N_NODES 8000
#define N_EDGES 24000

#define INV_SQRT3f 0.57735026918962576f
#define PW_MSG0f 0.10206207261596575f   /* sqrt(1/96) */
#define PW1f     0.10206207261596575f   /* PW_MSG1*INV_SQRT3 == sqrt(1/96) */
#define PW_G01f  0.022097086912079608f  /* sqrt(1/2048) */
#define PW_G2f   0.034232659844072866f  /* sqrt(3/2560) */
#define PW_H0f   0.031008683647302115f  /* sqrt(1/1040) */
#define PW_H1f   0.30618621784789724f   /* sqrt(3/32) */
#define RSQRT128f 0.08838834764831845f
#define RSQRT32f  0.17677669529663687f

typedef short short8 __attribute__((ext_vector_type(8)));
typedef float f32x4 __attribute__((ext_vector_type(4)));

__device__ inline short f32_to_bf16_bits(float v) {
  unsigned int b = __builtin_bit_cast(unsigned int, v);
  b += 0x7fffu + ((b >> 16) & 1u);        // RNE (no NaN inputs here)
  return (short)(b >> 16);
}

// ---------------- K1: edge MLP hidden layer -> bf16 ----------------
__global__ __launch_bounds__(256) void k1_h(const float* __restrict__ ea,
                                            const float* __restrict__ W1,
                                            short* __restrict__ hbf,
                                            float cst_silu) {
  int idx = blockIdx.x * 256 + threadIdx.x;          // e*128 + r, exact grid
  int e = idx >> 7, r = idx & 127;
  float s = 0.5f * (ea[e*4+0]*W1[r] + ea[e*4+1]*W1[128+r] +
                    ea[e*4+2]*W1[256+r] + ea[e*4+3]*W1[384+r]);
  float sg = 1.f / (1.f + expf(-s));
  hbf[idx] = f32_to_bf16_bits(cst_silu * s * sg * RSQRT128f);
}

// ---------------- W2 -> W2T bf16 [4608][128] ----------------
__global__ __launch_bounds__(256) void k_w2t(const float* __restrict__ W2,
                                             short* __restrict__ w2t) {
  int idx = blockIdx.x * 256 + threadIdx.x;          // 589824 exact
  int c = idx >> 7, k = idx & 127;
  w2t[idx] = f32_to_bf16_bits(W2[k*4608 + c]);
}

// ---------------- Wg* -> bf16 B-tables [col][k] for k3 ----------------
__global__ __launch_bounds__(256) void k_wgt(const float* __restrict__ Wg000,
                                             const float* __restrict__ Wg110,
                                             const float* __restrict__ Wg001,
                                             const float* __restrict__ Wg111,
                                             const float* __restrict__ Wg012,
                                             const float* __restrict__ Wg102,
                                             short* __restrict__ bt) {
  int i = blockIdx.x * 256 + threadIdx.x;            // < 196608 exact
  float v;
  if (i < 16384) {
    int col = i >> 6, vv = i & 63, u = col >> 4, w = col & 15;
    v = Wg000[u*1024 + vv*16 + w];
  } else if (i < 49152) {
    int j = i - 16384; int col = j >> 6, vv = j & 63, u = col >> 5, w = col & 31;
    v = Wg001[u*2048 + vv*32 + w];
  } else if (i < 65536) {
    int j = i - 49152; int col = j >> 5, vv = j & 31, u = col >> 4, w = col & 15;
    v = INV_SQRT3f * Wg110[u*512 + vv*16 + w];
  } else if (i < 98304) {
    int j = i - 65536; int col = j >> 5, vv = j & 31, u = col >> 5, w = col & 31;
    v = INV_SQRT3f * Wg111[u*1024 + vv*32 + w];
  } else if (i < 131072) {
    int j = i - 98304; int col = j >> 5, u = j & 31, vv = col >> 5, w = col & 31;
    v = (u < 16) ? Wg012[u*1024 + vv*32 + w] : 0.f;
  } else {
    int j = i - 131072; int col = j >> 6, vv = j & 63, u = col >> 5, w = col & 31;
    v = Wg102[u*2048 + vv*32 + w];
  }
  bt[i] = f32_to_bf16_bits(v);
}

// ---------------- K2: MFMA edge GEMM, pipelined B, fold, scatter -----------
// Unified 72-tile loop per wave. Tile id = wv + 4t; B row = id*16+nn+C,
// C = 0 (id<64, s000) / +3072 (id<96, s110) / -512 (s011, s101).
// Register double-buffer: tile t+1's 4 B-loads issue before tile t's MFMAs.
__global__ __launch_bounds__(256) void k2_edge_msg(const float* __restrict__ x,
                                                   const float* __restrict__ ea,
                                                   const short* __restrict__ w2t,
                                                   const short* __restrict__ hbf,
                                                   const int* __restrict__ ei,
                                                   float* __restrict__ nm) {
  __shared__ float msg_s[32][116];     // pad 116: flush conflicts 4->2-way
  __shared__ float x0pt[64][32];       // [u][e] PW1*xs0
  __shared__ float z2wt[32][32];       // [u][e] PW0*inv3*(xs1[u].a1)
  __shared__ float x1wt[32][32][3];    // [u][e][m] PW1*a0*xs1[u][m]
  __shared__ float a_s[32][4];
  __shared__ int srcs_s[32], dsts_s[32];

  const int tid = threadIdx.x;
  const int e0 = blockIdx.x * 32;

  if (tid < 32) { srcs_s[tid] = ei[e0+tid]; dsts_s[tid] = ei[N_EDGES + e0 + tid]; }
  if (tid < 128) a_s[tid>>2][tid&3] = ea[e0*4 + tid];
  for (int i = tid; i < 32*116; i += 256) (&msg_s[0][0])[i] = 0.f;
  __syncthreads();

  for (int i = tid; i < 2048; i += 256) {      // coalesced x0 gather
    int e = i >> 6, u = i & 63;
    x0pt[u][e] = PW1f * x[srcs_s[e]*160 + u];
  }
  for (int i = tid; i < 1024; i += 256) {
    int e = i >> 5, u = i & 31;
    const float* xp = &x[srcs_s[e]*160 + 64 + u*3];
    float m0v = xp[0], m1v = xp[1], m2v = xp[2];
    float a0 = a_s[e][0];
    z2wt[u][e] = PW_MSG0f * INV_SQRT3f *
                 (m0v*a_s[e][1] + m1v*a_s[e][2] + m2v*a_s[e][3]);
    x1wt[u][e][0] = PW1f * a0 * m0v;
    x1wt[u][e][1] = PW1f * a0 * m1v;
    x1wt[u][e][2] = PW1f * a0 * m2v;
  }
  __syncthreads();

  const int lane = tid & 63, wv = tid >> 6;
  const int quad = lane >> 4, nn = lane & 15;
  const int eq = quad * 4;

  short8 af[2][4];
#pragma unroll
  for (int t = 0; t < 2; ++t)
#pragma unroll
    for (int ks = 0; ks < 4; ++ks)
      af[t][ks] = *(const short8*)&hbf[(e0 + t*16 + nn)*128 + ks*32 + quad*8];

  float p000[2][4] = {};      // region 000, x0pt fold (x a0 at flush)
  float p0[2][4] = {};        // region 110, z2wt fold
  float p011[2][4] = {};      // region 011, x0pt fold (x a1[m] at flush)
  float p101[2][4][3] = {};   // region 101, x1wt fold

  // preload tile t=0 (id = wv, region 000)
  const short* bp0 = w2t + (wv*16 + nn)*128 + quad*8;
  short8 bc0 = *(const short8*)(bp0);
  short8 bc1 = *(const short8*)(bp0 + 32);
  short8 bc2 = *(const short8*)(bp0 + 64);
  short8 bc3 = *(const short8*)(bp0 + 96);

  for (int t = 0; t < 72; ++t) {
    const int id = wv + 4*t;
    // prefetch tile t+1 (id+4 <= 291 -> row <= 4159 < 4608, always in-bounds)
    const int idn = id + 4;
    const int Cn = (idn < 64) ? 0 : (idn < 96) ? 3072 : -512;
    const short* np = w2t + (idn*16 + nn + Cn)*128 + quad*8;
    short8 bn0 = *(const short8*)(np);
    short8 bn1 = *(const short8*)(np + 32);
    short8 bn2 = *(const short8*)(np + 64);
    short8 bn3 = *(const short8*)(np + 96);

    f32x4 c0 = {0.f,0.f,0.f,0.f}, c1 = {0.f,0.f,0.f,0.f};
    c0 = __builtin_amdgcn_mfma_f32_16x16x32_bf16(af[0][0], bc0, c0, 0,0,0);
    c1 = __builtin_amdgcn_mfma_f32_16x16x32_bf16(af[1][0], bc0, c1, 0,0,0);
    c0 = __builtin_amdgcn_mfma_f32_16x16x32_bf16(af[0][1], bc1, c0, 0,0,0);
    c1 = __builtin_amdgcn_mfma_f32_16x16x32_bf16(af[1][1], bc1, c1, 0,0,0);
    c0 = __builtin_amdgcn_mfma_f32_16x16x32_bf16(af[0][2], bc2, c0, 0,0,0);
    c1 = __builtin_amdgcn_mfma_f32_16x16x32_bf16(af[1][2], bc2, c1, 0,0,0);
    c0 = __builtin_amdgcn_mfma_f32_16x16x32_bf16(af[0][3], bc3, c0, 0,0,0);
    c1 = __builtin_amdgcn_mfma_f32_16x16x32_bf16(af[1][3], bc3, c1, 0,0,0);

    if (t < 16) {                       // region 000, u = id
      const int u = id;
      const f32x4 w0 = *(const f32x4*)&x0pt[u][eq];
      const f32x4 w1 = *(const f32x4*)&x0pt[u][16 + eq];
#pragma unroll
      for (int r = 0; r < 4; ++r) { p000[0][r] += w0[r]*c0[r]; p000[1][r] += w1[r]*c1[r]; }
    } else if (t < 24) {                // region 110, u = id-64
      const int u = id - 64;
      const f32x4 w0 = *(const f32x4*)&z2wt[u][eq];
      const f32x4 w1 = *(const f32x4*)&z2wt[u][16 + eq];
#pragma unroll
      for (int r = 0; r < 4; ++r) { p0[0][r] += w0[r]*c0[r]; p0[1][r] += w1[r]*c1[r]; }
    } else if (t < 56) {                // region 011, u = (id-96)>>1
      const int u = (id - 96) >> 1;
      const f32x4 w0 = *(const f32x4*)&x0pt[u][eq];
      const f32x4 w1 = *(const f32x4*)&x0pt[u][16 + eq];
#pragma unroll
      for (int r = 0; r < 4; ++r) { p011[0][r] += w0[r]*c0[r]; p011[1][r] += w1[r]*c1[r]; }
    } else {                            // region 101, u = (id-224)>>1
      const int u = (id - 224) >> 1;
#pragma unroll
      for (int r = 0; r < 4; ++r) {
        const float* xw0 = &x1wt[u][eq + r][0];
        const float* xw1 = &x1wt[u][16 + eq + r][0];
        p101[0][r][0] += xw0[0]*c0[r]; p101[0][r][1] += xw0[1]*c0[r]; p101[0][r][2] += xw0[2]*c0[r];
        p101[1][r][0] += xw1[0]*c1[r]; p101[1][r][1] += xw1[1]*c1[r]; p101[1][r][2] += xw1[2]*c1[r];
      }
    }
    bc0 = bn0; bc1 = bn1; bc2 = bn2; bc3 = bn3;
  }

  // flush register partials -> msg_s (cross-wave accumulate)
  const int wcol = (wv & 1)*16 + nn;
#pragma unroll
  for (int t = 0; t < 2; ++t)
#pragma unroll
    for (int r = 0; r < 4; ++r) {
      const int e = t*16 + eq + r;
      atomicAdd(&msg_s[e][nn], a_s[e][0]*p000[t][r] + p0[t][r]);
      const float q = p011[t][r];
      atomicAdd(&msg_s[e][16 + wcol*3 + 0], a_s[e][1]*q + p101[t][r][0]);
      atomicAdd(&msg_s[e][16 + wcol*3 + 1], a_s[e][2]*q + p101[t][r][1]);
      atomicAdd(&msg_s[e][16 + wcol*3 + 2], a_s[e][3]*q + p101[t][r][2]);
    }
  __syncthreads();

  for (int i = tid; i < 32*112; i += 256) {
    int le = i / 112, slot = i - le*112;
    atomicAdd(&nm[dsts_s[le]*112 + slot], msg_s[le][slot]);
  }
}

// ---------------- K3: node gate stage via MFMA, pipelined B ----------------
__global__ __launch_bounds__(256) void k3_gate(const float* __restrict__ x,
                                               const float* __restrict__ nm,
                                               const short* __restrict__ bt,
                                               float* __restrict__ xg,
                                               float cst_sig, float cst_tanh) {
  __shared__ short x0b[16][64];       // bf16 A: x0
  __shared__ short x1b[3][16][32];    // bf16 A: x1 per m
  __shared__ short m0b[16][32];       // bf16 A: m0 (K-padded with zeros)
  __shared__ float m0t[16][16];       // [u][n] fold coeff
  __shared__ float m1t[32][3][16];    // [u][m][n]
  __shared__ float x1t[32][3][16];    // [v][m][n]
  __shared__ float gs_s[16][20];      // padded rows: 2-way conflicts only
  __shared__ float gg_s[16][36];
  __shared__ float gv_s[16][100];
  const int tid = threadIdx.x;
  const int n0 = blockIdx.x * 16;

  for (int i = tid; i < 16*160; i += 256) {
    int n = i / 160, f = i - n*160;
    float v = x[(n0+n)*160 + f];
    if (f < 64) x0b[n][f] = f32_to_bf16_bits(v);
    else {
      int j = f - 64; int vv = j/3, m = j - vv*3;
      x1b[m][n][vv] = f32_to_bf16_bits(v);
      x1t[vv][m][n] = v;
    }
  }
  for (int i = tid; i < 16*112; i += 256) {
    int n = i / 112, f = i - n*112;
    float v = nm[(n0+n)*112 + f];
    if (f < 16) { m0b[n][f] = f32_to_bf16_bits(v); m0t[f][n] = v; }
    else { int j = f - 16; int u = j/3, m = j - u*3; m1t[u][m][n] = v; }
  }
  { int n = tid >> 4, k = tid & 15; m0b[n][16+k] = 0; }   // K-pad zeros
  for (int i = tid; i < 320; i += 256) (&gs_s[0][0])[i] = 0.f;
  for (int i = tid; i < 576; i += 256) (&gg_s[0][0])[i] = 0.f;
  for (int i = tid; i < 1600; i += 256) (&gv_s[0][0])[i] = 0.f;
  __syncthreads();

  const int lane = tid & 63, wv = tid >> 6;
  const int quad = lane >> 4, nn = lane & 15;
  const int eq = quad * 4;
  const int wh = wv & 1;

  const short8 ax0a = *(const short8*)&x0b[nn][quad*8];
  const short8 ax0c = *(const short8*)&x0b[nn][32 + quad*8];
  short8 ax1[3];
#pragma unroll
  for (int m = 0; m < 3; ++m) ax1[m] = *(const short8*)&x1b[m][nn][quad*8];
  const short8 am0 = *(const short8*)&m0b[nn][quad*8];

  const short* b000 = bt;
  const short* b001 = bt + 16384;
  const short* b110 = bt + 49152;
  const short* b111 = bt + 65536;
  const short* b012 = bt + 98304;
  const short* b102 = bt + 131072;

  float gs_p[4] = {}, gg_p[4] = {};
  float gv_p[3][4] = {};

  // T000: gs, 4 iters, K=64
  {
    int u = wv;
    const short* p = b000 + (u*16 + nn)*64 + quad*8;
    short8 ba = *(const short8*)p, bb = *(const short8*)(p + 32);
    for (int i = 0; i < 4; ++i) {
      const int un = (i < 3) ? u + 4 : u;
      const short* np = b000 + (un*16 + nn)*64 + quad*8;
      short8 na = *(const short8*)np, nb2 = *(const short8*)(np + 32);
      f32x4 c = {0.f,0.f,0.f,0.f};
      c = __builtin_amdgcn_mfma_f32_16x16x32_bf16(ax0a, ba, c, 0,0,0);
      c = __builtin_amdgcn_mfma_f32_16x16x32_bf16(ax0c, bb, c, 0,0,0);
      const f32x4 t = *(const f32x4*)&m0t[u][eq];
#pragma unroll
      for (int r = 0; r < 4; ++r) gs_p[r] += t[r]*c[r];
      u = un; ba = na; bb = nb2;
    }
  }
  // T110: gs, 3 x 8 iters, K=32
#pragma unroll
  for (int m = 0; m < 3; ++m) {
    int u = wv;
    const short* p = b110 + (u*16 + nn)*32 + quad*8;
    short8 ba = *(const short8*)p;
    for (int i = 0; i < 8; ++i) {
      const int un = (i < 7) ? u + 4 : u;
      const short* np = b110 + (un*16 + nn)*32 + quad*8;
      short8 na = *(const short8*)np;
      f32x4 c = {0.f,0.f,0.f,0.f};
      c = __builtin_amdgcn_mfma_f32_16x16x32_bf16(ax1[m], ba, c, 0,0,0);
      const f32x4 t = *(const f32x4*)&m1t[u][m][eq];
#pragma unroll
      for (int r = 0; r < 4; ++r) gs_p[r] += t[r]*c[r];
      u = un; ba = na;
    }
  }
  // T001: gg, 16 iters, K=64
  {
    int t2 = wv;
    const short* p = b001 + ((t2>>1)*32 + wh*16 + nn)*64 + quad*8;
    short8 ba = *(const short8*)p, bb = *(const short8*)(p + 32);
    for (int i = 0; i < 16; ++i) {
      const int t2n = (i < 15) ? t2 + 4 : t2;
      const short* np = b001 + ((t2n>>1)*32 + wh*16 + nn)*64 + quad*8;
      short8 na = *(const short8*)np, nb2 = *(const short8*)(np + 32);
      f32x4 c = {0.f,0.f,0.f,0.f};
      c = __builtin_amdgcn_mfma_f32_16x16x32_bf16(ax0a, ba, c, 0,0,0);
      c = __builtin_amdgcn_mfma_f32_16x16x32_bf16(ax0c, bb, c, 0,0,0);
      const f32x4 t = *(const f32x4*)&m0t[t2>>1][eq];
#pragma unroll
      for (int r = 0; r < 4; ++r) gg_p[r] += t[r]*c[r];
      t2 = t2n; ba = na; bb = nb2;
    }
  }
  // T111: gg, 3 x 16 iters, K=32
#pragma unroll
  for (int m = 0; m < 3; ++m) {
    int t2 = wv;
    const short* p = b111 + ((t2>>1)*32 + wh*16 + nn)*32 + quad*8;
    short8 ba = *(const short8*)p;
    for (int i = 0; i < 16; ++i) {
      const int t2n = (i < 15) ? t2 + 4 : t2;
      const short* np = b111 + ((t2n>>1)*32 + wh*16 + nn)*32 + quad*8;
      short8 na = *(const short8*)np;
      f32x4 c = {0.f,0.f,0.f,0.f};
      c = __builtin_amdgcn_mfma_f32_16x16x32_bf16(ax1[m], ba, c, 0,0,0);
      const f32x4 t = *(const f32x4*)&m1t[t2>>1][m][eq];
#pragma unroll
      for (int r = 0; r < 4; ++r) gg_p[r] += t[r]*c[r];
      t2 = t2n; ba = na;
    }
  }
  // T012: gv, 16 iters, K=32 (A = m0)
  {
    int t2 = wv;
    const short* p = b012 + ((t2>>1)*32 + wh*16 + nn)*32 + quad*8;
    short8 ba = *(const short8*)p;
    for (int i = 0; i < 16; ++i) {
      const int t2n = (i < 15) ? t2 + 4 : t2;
      const short* np = b012 + ((t2n>>1)*32 + wh*16 + nn)*32 + quad*8;
      short8 na = *(const short8*)np;
      f32x4 c = {0.f,0.f,0.f,0.f};
      c = __builtin_amdgcn_mfma_f32_16x16x32_bf16(am0, ba, c, 0,0,0);
      const int v = t2 >> 1;
#pragma unroll
      for (int m = 0; m < 3; ++m) {
        const f32x4 t = *(const f32x4*)&x1t[v][m][eq];
#pragma unroll
        for (int r = 0; r < 4; ++r) gv_p[m][r] += t[r]*c[r];
      }
      t2 = t2n; ba = na;
    }
  }
  // T102: gv, 16 iters, K=64
  {
    int t2 = wv;
    const short* p = b102 + ((t2>>1)*32 + wh*16 + nn)*64 + quad*8;
    short8 ba = *(const short8*)p, bb = *(const short8*)(p + 32);
    for (int i = 0; i < 16; ++i) {
      const int t2n = (i < 15) ? t2 + 4 : t2;
      const short* np = b102 + ((t2n>>1)*32 + wh*16 + nn)*64 + quad*8;
      short8 na = *(const short8*)np, nb2 = *(const short8*)(np + 32);
      f32x4 c = {0.f,0.f,0.f,0.f};
      c = __builtin_amdgcn_mfma_f32_16x16x32_bf16(ax0a, ba, c, 0,0,0);
      c = __builtin_amdgcn_mfma_f32_16x16x32_bf16(ax0c, bb, c, 0,0,0);
      const int u = t2 >> 1;
#pragma unroll
      for (int m = 0; m < 3; ++m) {
        const f32x4 t = *(const f32x4*)&m1t[u][m][eq];
#pragma unroll
        for (int r = 0; r < 4; ++r) gv_p[m][r] += t[r]*c[r];
      }
      t2 = t2n; ba = na; bb = nb2;
    }
  }

  // cross-wave combine
#pragma unroll
  for (int r = 0; r < 4; ++r) {
    atomicAdd(&gs_s[eq + r][nn], gs_p[r]);
    atomicAdd(&gg_s[eq + r][wh*16 + nn], gg_p[r]);
#pragma unroll
    for (int m = 0; m < 3; ++m)
      atomicAdd(&gv_s[eq + r][(wh*16 + nn)*3 + m], gv_p[m][r]);
  }
  __syncthreads();

  for (int i = tid; i < 16*112; i += 256) {
    int n = i / 112, f = i - n*112;
    float o;
    if (f < 16) {
      o = cst_sig / (1.f + expf(-PW_G01f * gs_s[n][f]));
    } else {
      int j = f - 16; int w = j/3;
      float gate = cst_tanh * tanhf(PW_G01f * gg_s[n][w]);
      o = gate * (PW_G2f * INV_SQRT3f) * gv_s[n][j];
    }
    xg[(n0+n)*112 + f] = o;
  }
}

// ---------------- K4: masked canonical pooling ----------------
__global__ __launch_bounds__(256) void k4_pool(const float* __restrict__ xg,
                                               const int* __restrict__ z,
                                               const int* __restrict__ canonical,
                                               float* __restrict__ sums,
                                               float* __restrict__ cnt) {
  int idx = blockIdx.x * 256 + threadIdx.x;
  int n = idx / 112, slot = idx - n*112;
  if (z[n] > 1) {
    int c = canonical[n];
    atomicAdd(&sums[c*112 + slot], xg[idx]);
    if (slot == 0) atomicAdd(&cnt[c], 1.f);
  }
}

// ---------------- K5: quadratic head -> th ----------------
__global__ __launch_bounds__(256) void k5_thead(const float* __restrict__ sums,
                                                const float* __restrict__ cnt,
                                                const float* __restrict__ Wa,
                                                const float* __restrict__ Wb,
                                                const float* __restrict__ Wc,
                                                const float* __restrict__ Wd,
                                                float* __restrict__ th) {
  __shared__ float xh_s[8][112];
  __shared__ float cm_s[8][1024];
  const int tid = threadIdx.x;
  const int n0 = blockIdx.x * 8;
  for (int i = tid; i < 8*112; i += 256) {
    int n = i / 112, j = i - n*112;
    float cv = fmaxf(cnt[n0+n], 1.f);
    xh_s[n][j] = sums[(n0+n)*112 + j] / cv;
  }
  __syncthreads();
  for (int i = tid; i < 8192; i += 256) {
    int n = i >> 10, uv = i & 1023, u = uv >> 5, v = uv & 31;
    const float* hh = xh_s[n] + 16;
    cm_s[n][uv] = hh[u*3]*hh[v*3] + hh[u*3+1]*hh[v*3+1] + hh[u*3+2]*hh[v*3+2];
  }
  __syncthreads();
  if (tid < 128) {
    int n = tid >> 4, k = tid & 15;
    float sA = 0.f;
    for (int v = 0; v < 16; ++v) sA += Wa[k*16+v]*xh_s[n][v];
    float wd = 0.f;
    const float* cp = cm_s[n];
#pragma unroll 4
    for (int uv = 0; uv < 1024; ++uv) wd += cp[uv]*Wd[uv*16 + k];
    th[(n0+n)*112 + k] = PW_H0f*(xh_s[n][k]*sA + INV_SQRT3f*wd);
  }
  {
    int n = tid >> 5, j = tid & 31;
    float wb = 0.f, wc = 0.f;
    for (int u = 0; u < 16; ++u) wb += Wb[u*32+j]*xh_s[n][u];
    for (int v = 0; v < 16; ++v) wc += Wc[j*16+v]*xh_s[n][v];
    float cb = PW_H1f * INV_SQRT3f * (wb + wc);
    const float* hh = xh_s[n] + 16;
    float* o = th + (n0+n)*112 + 16 + j*3;
    o[0] = cb*hh[j*3]; o[1] = cb*hh[j*3+1]; o[2] = cb*hh[j*3+2];
  }
}

// ---------------- K6: select + output linear ----------------
__global__ __launch_bounds__(256) void k6_out(const float* __restrict__ xg,
                                              const float* __restrict__ th,
                                              const int* __restrict__ z,
                                              const int* __restrict__ canonical,
                                              const float* __restrict__ WL0,
                                              const float* __restrict__ WL1,
                                              float* __restrict__ out) {
  int idx = blockIdx.x * 256 + threadIdx.x;
  int n = idx / 112, j = idx - n*112;
  const float* yr = (z[n] > 1) ? (th + canonical[n]*112) : (xg + n*112);
  float o = 0.f;
  if (j < 16) {
    for (int v = 0; v < 16; ++v) o += yr[v]*WL0[v*16 + j];
    o *= 0.25f;
  } else {
    int jj = j - 16, w = jj / 3, m = jj - w*3;
    for (int u = 0; u < 32; ++u) o += yr[16 + u*3 + m]*WL1[u*32 + w];
    o *= RSQRT32f;
  }
  out[idx] = o;
}

// ---------------- host: replicate numpy's trapz normalization constants ----
namespace {
struct Csts {
  float silu, sig, tanh_;
  Csts() {
    const int NPT = 200001;
    const double a = -12.0, b = 12.0;
    const double dx = (b - a) / (NPT - 1);
    double s1 = 0.0, s2 = 0.0, s3 = 0.0;
    for (int i = 0; i < NPT; ++i) {
      double xv = a + dx*i;
      double pdf = std::exp(-0.5*xv*xv) / std::sqrt(2.0*M_PI);
      double sg = 1.0 / (1.0 + std::exp(-xv));
      double f1 = xv*sg, f2 = sg, f3 = std::tanh(xv);
      double wg = (i == 0 || i == NPT-1) ? 0.5 : 1.0;
      s1 += wg*f1*f1*pdf; s2 += wg*f2*f2*pdf; s3 += wg*f3*f3*pdf;
    }
    silu  = (float)(1.0/std::sqrt(s1*dx));
    sig   = (float)(1.0/std::sqrt(s2*dx));
    tanh_ = (float)(1.0/std::sqrt(s3*dx));
  }
};
}  // namespace

extern "C" void kernel_launch(void* const* d_in, const int* in_sizes, int n_in,
                              void* d_out, int out_size, void* d_ws, size_t ws_size,
                              hipStream_t stream) {
  const float* x     = (const float*)d_in[0];
  const float* ea    = (const float*)d_in[1];
  const float* W1    = (const float*)d_in[2];
  const float* W2    = (const float*)d_in[3];
  const float* Wg000 = (const float*)d_in[4];
  const float* Wg110 = (const float*)d_in[5];
  const float* Wg001 = (const float*)d_in[6];
  const float* Wg111 = (const float*)d_in[7];
  const float* Wg012 = (const float*)d_in[8];
  const float* Wg102 = (const float*)d_in[9];
  const float* Wa    = (const float*)d_in[10];
  const float* Wb    = (const float*)d_in[11];
  const float* Wc    = (const float*)d_in[12];
  const float* Wd    = (const float*)d_in[13];
  const float* WL0   = (const float*)d_in[14];
  const float* WL1   = (const float*)d_in[15];
  const int* ei      = (const int*)d_in[16];
  const int* z       = (const int*)d_in[17];
  const int* canonical = (const int*)d_in[18];
  float* out = (float*)d_out;

  float* ws   = (float*)d_ws;
  short* hbf  = (short*)ws;            // 3,072,000 bf16
  short* w2t  = (short*)(ws + 1536000);//   589,824 bf16
  short* bt   = (short*)(ws + 1831000);//   196,608 bf16 gate B-tables
  float* nm   = ws + 1930000;          //   896,000
  float* xg   = ws + 2826000;          //   896,000
  float* sums = ws + 3722000;          //   896,000
  float* cnt  = ws + 4618000;          //     8,000 (contiguous after sums)
  float* th   = ws + 4626000;          //   896,000

  static const Csts C;                 // host-only; safe under graph capture

  hipMemsetAsync(nm, 0, 896000*sizeof(float), stream);
  hipMemsetAsync(sums, 0, (896000+8000)*sizeof(float), stream);

  k1_h<<<12000, 256, 0, stream>>>(ea, W1, hbf, C.silu);
  k_w2t<<<2304, 256, 0, stream>>>(W2, w2t);
  k_wgt<<<768, 256, 0, stream>>>(Wg000, Wg110, Wg001, Wg111, Wg012, Wg102, bt);
  k2_edge_msg<<<750, 256, 0, stream>>>(x, ea, w2t, hbf, ei, nm);
  k3_gate<<<500, 256, 0, stream>>>(x, nm, bt, xg, C.sig, C.tanh_);
  k4_pool<<<3500, 256, 0, stream>>>(xg, z, canonical, sums, cnt);
  k5_thead<<<1000, 256, 0, stream>>>(sums, cnt, Wa, Wb, Wc, Wd, th);
  k6_out<<<3500, 256, 0, stream>>>(xg, th, z, canonical, WL0, WL1, out);
}